// Round 6
// baseline (262.801 us; speedup 1.0000x reference)
//
#include <hip/hip_runtime.h>

// InterNet B=32,N=16,D=64,P=8. R21: single fused per-image kernel.
// Insight from R20 counters: k2 was latency-bound on the cA/cB gather
// round-trip (16MB w + 16MB scattered r) while MFMA sat at 7% util.
// Flip cache->recompute: per image, loop over the ~7.5 active pairs and
// recompute conv(mask*[y1;y2],W_rel) = 128-ic MFMA conv on [x[o1]|x[o2]]
// staged from L2 (same-XCD batch). Deletes k1, cA/cB, one launch gap,
// and cA/cB's bf16 rounding (precision improves).
//   Wave split: group0 (waves 0-3) = even pairs + self/aff/agg;
//   group1 (waves 4-7) = odd pairs; each wave keeps f[4] accumulator ILP
//   (R20 lesson: f[2] halves MFMA chain ILP -> latency-bound).
//   Group1's pair-sum joins via one fp32 LDS exchange at the end.
// 2 dispatches: prep_w (tiny) + kmain<<<512,512>>> (2 blocks/CU, 62.6KB LDS).

#define NIMG 512
#define IMGSZ 4096

using bf16x8 = __attribute__((ext_vector_type(8))) short;
using f32x4  = __attribute__((ext_vector_type(4))) float;

__device__ inline unsigned short f2bf(float f) {
  union { float f; unsigned u; } v; v.f = f;
  unsigned r = v.u + 0x7fffu + ((v.u >> 16) & 1u);
  return (unsigned short)(r >> 16);
}

// Wt slots: self [9][64][64] @0, aff @36864, rel [9][64][128] @73728,
//           agg [9][64][128] @147456.
__global__ __launch_bounds__(256) void prep_w(
    const float* __restrict__ Wr, const float* __restrict__ Ws,
    const float* __restrict__ Wa, const float* __restrict__ Wg,
    unsigned short* __restrict__ Wt)
{
  int i4 = (blockIdx.x * 256 + threadIdx.x) * 4;
  if (i4 >= 221184) return;
  unsigned short o4[4];
#pragma unroll
  for (int e = 0; e < 4; ++e) {
    int idx = i4 + e;
    float v;
    if (idx < 73728) {
      int c = idx / 36864, r = idx % 36864;
      int t = r >> 12, oc = (r >> 6) & 63, ic = r & 63;
      v = (c == 0 ? Ws : Wa)[oc * 576 + ic * 9 + t];
    } else {
      int r2 = idx - 73728;
      int half = r2 / 73728, rr = r2 % 73728;
      int t = rr >> 13, oc = (rr >> 7) & 63, ic = rr & 127;
      v = (half ? Wg : Wr)[oc * 1152 + ic * 9 + t];
    }
    o4[e] = f2bf(v);
  }
  uint2 pk;
  pk.x = (unsigned)o4[0] | ((unsigned)o4[1] << 16);
  pk.y = (unsigned)o4[2] | ((unsigned)o4[3] << 16);
  *(uint2*)(Wt + i4) = pk;
}

// batch b pinned to XCD b&7 (perf heuristic; correctness never depends on it)
__device__ inline void decode_img(int j, int& b, int& o) {
  b = ((j >> 7) << 3) | (j & 7);
  o = (j >> 3) & 15;
}

// stage x (fp32 [ic][px]) -> LDS bf16 [px][stride ROWX], cols at +coff.
// 512-thread version: 4 u32 per thread.
template<int ROWX>
__device__ inline void stage_x512(const float* __restrict__ xb,
                                  unsigned short* __restrict__ s,
                                  int coff, int w8, int px) {
#pragma unroll
  for (int r = 0; r < 4; ++r) {
    int ic0 = (w8 + 8 * r) * 2;
    const float* sp = xb + ic0 * 64;
    float a = sp[px], c = sp[64 + px];
    *(unsigned*)(s + px * ROWX + coff + ic0) =
        (unsigned)f2bf(a) | ((unsigned)f2bf(c) << 16);
  }
}

// stage pair (x[o1] -> cols 0..63, x[o2] -> cols 64..127), 256 thr/group
__device__ inline void stage_pair(const float* __restrict__ x1,
                                  const float* __restrict__ x2,
                                  unsigned short* __restrict__ buf,
                                  int w4, int px) {
#pragma unroll
  for (int r = 0; r < 8; ++r) {
    int ic0 = (w4 + 4 * r) * 2;
    const float* sp = x1 + ic0 * 64;
    float a = sp[px], c = sp[64 + px];
    *(unsigned*)(buf + px * 136 + ic0) =
        (unsigned)f2bf(a) | ((unsigned)f2bf(c) << 16);
  }
#pragma unroll
  for (int r = 0; r < 8; ++r) {
    int ic0 = (w4 + 4 * r) * 2;
    const float* sp = x2 + ic0 * 64;
    float a = sp[px], c = sp[64 + px];
    *(unsigned*)(buf + px * 136 + 64 + ic0) =
        (unsigned)f2bf(a) | ((unsigned)f2bf(c) << 16);
  }
}

__global__ __launch_bounds__(512, 4) void kmain(
    const float* __restrict__ x,
    const int* __restrict__ g_idx,
    const unsigned short* __restrict__ Wt,
    const float* __restrict__ b_rel, const float* __restrict__ b_self,
    const float* __restrict__ b_aff, const float* __restrict__ b_agg,
    float* __restrict__ out)
{
  constexpr int ROW = 72, ROW2 = 136;
  __shared__ __align__(16) unsigned short sX[65 * ROW2];       // [a | x] bf16
  __shared__ __align__(16) unsigned short sPred[65 * ROW];     // pred bf16
  __shared__ __align__(16) unsigned short sPair[2][65 * ROW2]; // per-group pair buf
  __shared__ int so1a[16], so2a[16];                           // compacted m=1 pairs
  __shared__ int s_na;

  int b, i;
  decode_img(blockIdx.x, b, i);
  const int img = b * 16 + i;
  const int tid = threadIdx.x;
  const int grp = tid >> 8;          // 0: waves 0-3 (even pairs + convs), 1: odd pairs
  const int w8 = tid >> 6, lane = tid & 63;
  const int w4 = w8 & 3;             // oc quarter within group
  const float* xbase = x + (size_t)b * 16 * IMGSZ;

  // ---- mask compaction (wave 0): g_idx col2 is exactly 0/1, block-uniform.
  // m=0 pairs contribute the constant relu(b_rel); only m=1 pairs staged.
  int o1v = 0, o2v = 0, mv = 0;
  if (tid < 15) {
    const int* gp = g_idx + ((size_t)b * 240 + i * 15 + tid) * 3;
    o1v = gp[0] & 15;   // tile(x, n-1): x1[j] = x[j % 16]
    o2v = gp[1] & 15;
    mv  = gp[2];
  }
  if (tid < 64) {
    unsigned long long mk = __ballot(mv != 0);
    int pfx = (int)__popcll(mk & ((1ull << tid) - 1));
    if (mv) { so1a[pfx] = o1v; so2a[pfx] = o2v; }
    if (tid == 0) s_na = (int)__popcll(mk);
  }

  stage_x512<ROW2>(x + (size_t)img * IMGSZ, sX, 64, w8, lane);
  if (tid < 68) ((unsigned*)(sX + 64 * ROW2))[tid] = 0;
  if (tid < 36) ((unsigned*)(sPred + 64 * ROW))[tid] = 0;
  if (tid < 136) {                   // zero both pair-buffer pad rows (once)
    int g = tid / 68, c = tid % 68;
    ((unsigned*)(sPair[g] + 64 * ROW2))[c] = 0;
  }
  __syncthreads();

  const int na = s_na;
  const int q = lane >> 4, n16 = lane & 15;
  const int ocb = w4 * 16;
  const int co = ocb + q * 4;
  const int aw64  = (ocb + n16) * 64 + q * 8;
  const int aw128 = (ocb + n16) * 128 + q * 8;

  int pyt[4], pxt[4];
#pragma unroll
  for (int t = 0; t < 4; ++t) { int p = t * 16 + n16; pyt[t] = p >> 3; pxt[t] = p & 7; }

  float br4[4];
#pragma unroll
  for (int r = 0; r < 4; ++r) br4[r] = b_rel[co + r];

  // pacc: group0 = xs + (15-na)*relu(br) + its pairs; group1 = its pairs.
  f32x4 pacc[4] = {};

  // ---- self conv (group0 only; group1 proceeds to stage its first pair)
  if (!grp) {
    f32x4 f[4] = {};
    const unsigned short* WS = Wt + aw64;
#pragma unroll
    for (int tap = 0; tap < 9; ++tap) {
      const int dy = tap / 3 - 1, dx = tap % 3 - 1;
      int spt[4];
#pragma unroll
      for (int t = 0; t < 4; ++t) {
        int sy = pyt[t] + dy, sx = pxt[t] + dx;
        spt[t] = ((unsigned)sy < 8u && (unsigned)sx < 8u) ? (sy * 8 + sx) : 64;
      }
#pragma unroll
      for (int ks = 0; ks < 2; ++ks) {
        bf16x8 a = *(const bf16x8*)(WS + tap * 4096 + ks * 32);
#pragma unroll
        for (int t = 0; t < 4; ++t) {
          bf16x8 bt = *(const bf16x8*)(sX + spt[t] * ROW2 + 64 + ks * 32 + q * 8);
          f[t] = __builtin_amdgcn_mfma_f32_16x16x32_bf16(a, bt, f[t], 0, 0, 0);
        }
      }
    }
    const float c0 = (float)(15 - na);
#pragma unroll
    for (int t = 0; t < 4; ++t)
#pragma unroll
      for (int r = 0; r < 4; ++r)
        pacc[t][r] = fmaxf(f[t][r] + b_self[co + r], 0.f)
                   + c0 * fmaxf(br4[r], 0.f);
  }

  // ---- pair loop: group g handles pairs j = 2*it + g on its own buffer.
  // niter uniform across block -> barriers uniform.
  {
    unsigned short* bufg = sPair[grp];
    const unsigned short* WR = Wt + 73728 + aw128;
    const int niter = (na + 1) >> 1;
#pragma unroll 1
    for (int it = 0; it < niter; ++it) {
      const int jc = 2 * it + grp;
      __syncthreads();               // own group's reads of bufg are done
      if (jc < na)
        stage_pair(xbase + (size_t)so1a[jc] * IMGSZ,
                   xbase + (size_t)so2a[jc] * IMGSZ, bufg, w4, lane);
      __syncthreads();               // bufg staged
      if (jc < na) {
        f32x4 pcc[4] = {};
#pragma unroll
        for (int tap = 0; tap < 9; ++tap) {
          const int dy = tap / 3 - 1, dx = tap % 3 - 1;
          int spt[4];
#pragma unroll
          for (int t = 0; t < 4; ++t) {
            int sy = pyt[t] + dy, sx = pxt[t] + dx;
            spt[t] = ((unsigned)sy < 8u && (unsigned)sx < 8u) ? (sy * 8 + sx) : 64;
          }
#pragma unroll
          for (int ks = 0; ks < 4; ++ks) {
            bf16x8 aa = *(const bf16x8*)(WR + tap * 8192 + ks * 32);
#pragma unroll
            for (int t = 0; t < 4; ++t) {
              bf16x8 bt = *(const bf16x8*)(bufg + spt[t] * ROW2 + ks * 32 + q * 8);
              pcc[t] = __builtin_amdgcn_mfma_f32_16x16x32_bf16(aa, bt, pcc[t], 0, 0, 0);
            }
          }
        }
#pragma unroll
        for (int t = 0; t < 4; ++t)
#pragma unroll
          for (int r = 0; r < 4; ++r)
            pacc[t][r] += fmaxf(pcc[t][r] + br4[r], 0.f);
      }
    }
  }
  __syncthreads();                   // last pair reads done; bufs reusable

  // ---- join: group1's pair-sum -> fp32 scratch (aliases sPair[0]); group0
  // adds and writes pred bf16 to sPred [px][ic].
  {
    float* scr = (float*)sPair[0];   // 64*68 f32 = 17408B <= 17680B
    if (grp) {
#pragma unroll
      for (int t = 0; t < 4; ++t)
        *(f32x4*)(scr + (t * 16 + n16) * 68 + co) = pacc[t];
    }
    __syncthreads();
    if (!grp) {
#pragma unroll
      for (int t = 0; t < 4; ++t) {
        int p = t * 16 + n16;
        f32x4 o2 = *(const f32x4*)(scr + p * 68 + co);
        float v0 = pacc[t][0] + o2[0], v1 = pacc[t][1] + o2[1];
        float v2 = pacc[t][2] + o2[2], v3 = pacc[t][3] + o2[3];
        uint2 pk;
        pk.x = (unsigned)f2bf(v0) | ((unsigned)f2bf(v1) << 16);
        pk.y = (unsigned)f2bf(v2) | ((unsigned)f2bf(v3) << 16);
        *(uint2*)(sPred + p * ROW + co) = pk;
      }
    }
  }
  __syncthreads();

  // ---- aff conv (group0): sPred -> a -> sX cols 0..63
  if (!grp) {
    f32x4 f[4] = {};
    const unsigned short* WA = Wt + 36864 + aw64;
#pragma unroll
    for (int tap = 0; tap < 9; ++tap) {
      const int dy = tap / 3 - 1, dx = tap % 3 - 1;
      int spt[4];
#pragma unroll
      for (int t = 0; t < 4; ++t) {
        int sy = pyt[t] + dy, sx = pxt[t] + dx;
        spt[t] = ((unsigned)sy < 8u && (unsigned)sx < 8u) ? (sy * 8 + sx) : 64;
      }
#pragma unroll
      for (int ks = 0; ks < 2; ++ks) {
        bf16x8 a = *(const bf16x8*)(WA + tap * 4096 + ks * 32);
#pragma unroll
        for (int t = 0; t < 4; ++t) {
          bf16x8 bt = *(const bf16x8*)(sPred + spt[t] * ROW + ks * 32 + q * 8);
          f[t] = __builtin_amdgcn_mfma_f32_16x16x32_bf16(a, bt, f[t], 0, 0, 0);
        }
      }
    }
#pragma unroll
    for (int t = 0; t < 4; ++t) {
      int p = t * 16 + n16;
      float v0 = fmaxf(f[t][0] + b_aff[co + 0], 0.f);
      float v1 = fmaxf(f[t][1] + b_aff[co + 1], 0.f);
      float v2 = fmaxf(f[t][2] + b_aff[co + 2], 0.f);
      float v3 = fmaxf(f[t][3] + b_aff[co + 3], 0.f);
      uint2 pk;
      pk.x = (unsigned)f2bf(v0) | ((unsigned)f2bf(v1) << 16);
      pk.y = (unsigned)f2bf(v2) | ((unsigned)f2bf(v3) << 16);
      *(uint2*)(sX + p * ROW2 + co) = pk;
    }
  }
  __syncthreads();

  // ---- agg conv (group0): sX (128 ic: [a|x]) -> out. Swapped MFMA
  // operands: lane owns 4 consecutive px of one oc -> coalesced float4.
  if (!grp) {
    f32x4 g[4] = {};
    const unsigned short* WG = Wt + 147456 + aw128;
#pragma unroll
    for (int tap = 0; tap < 9; ++tap) {
      const int dy = tap / 3 - 1, dx = tap % 3 - 1;
      int spt[4];
#pragma unroll
      for (int t = 0; t < 4; ++t) {
        int sy = pyt[t] + dy, sx = pxt[t] + dx;
        spt[t] = ((unsigned)sy < 8u && (unsigned)sx < 8u) ? (sy * 8 + sx) : 64;
      }
#pragma unroll
      for (int ks = 0; ks < 4; ++ks) {
        bf16x8 a = *(const bf16x8*)(WG + tap * 8192 + ks * 32);
#pragma unroll
        for (int t = 0; t < 4; ++t) {
          bf16x8 bt = *(const bf16x8*)(sX + spt[t] * ROW2 + ks * 32 + q * 8);
          g[t] = __builtin_amdgcn_mfma_f32_16x16x32_bf16(bt, a, g[t], 0, 0, 0);
        }
      }
    }
    float* ob = out + (size_t)img * IMGSZ;
    const float bg = b_agg[ocb + n16];
#pragma unroll
    for (int t = 0; t < 4; ++t) {
      f32x4 v;
#pragma unroll
      for (int r = 0; r < 4; ++r) v[r] = fmaxf(g[t][r] + bg, 0.f);
      *(f32x4*)(ob + (ocb + n16) * 64 + t * 16 + q * 4) = v;
    }
  }
}

extern "C" void kernel_launch(void* const* d_in, const int* in_sizes, int n_in,
                              void* d_out, int out_size, void* d_ws, size_t ws_size,
                              hipStream_t stream) {
  const float* x      = (const float*)d_in[0];
  const int*   g_idx  = (const int*)  d_in[1];
  const float* W_rel  = (const float*)d_in[2];
  const float* b_rel  = (const float*)d_in[3];
  const float* W_self = (const float*)d_in[4];
  const float* b_self = (const float*)d_in[5];
  const float* W_aff  = (const float*)d_in[6];
  const float* b_aff  = (const float*)d_in[7];
  const float* W_agg  = (const float*)d_in[8];
  const float* b_agg  = (const float*)d_in[9];
  float* out = (float*)d_out;

  unsigned short* Wt = (unsigned short*)d_ws;      // 221184 bf16

  prep_w<<<216, 256, 0, stream>>>(W_rel, W_self, W_aff, W_agg, Wt);
  kmain<<<NIMG, 512, 0, stream>>>(x, g_idx, Wt, b_rel, b_self, b_aff, b_agg,
                                  out);
}

// Round 7
// 115.844 us; speedup vs baseline: 2.2686x; 2.2686x over previous
//
#include <hip/hip_runtime.h>

// InterNet B=32,N=16,D=64,P=8. Factorized: conv(mask*[y1;y2],W_rel) =
// mask*(convA(x[o1]) + convB(x[o2])). 3 dispatches, no inter-block sync.
// R22 = R18 restored verbatim (verified 116.5us best). Structural search
// exhausted: coop-fusion (-137us), xs-migration (-3), t-split (-21),
// per-image recompute (-146) all regressed; R18 is the floor configuration.
//   k1: 512-thr blocks, waves 0-3 = convA, waves 4-7 = convB (each loads only
//       its weight half -> no duplicated weight traffic). 16 waves/CU.
//   k2: 512-thr blocks; all 8 waves stage + combine (2 passes); waves 4-7
//       idle at barriers during convs. 2 blocks/CU: 90KB LDS, VGPR<=128.
//   prep_w: 4 elems/thread, uint2 stores.

#define NIMG 512
#define IMGSZ 4096

using bf16x8 = __attribute__((ext_vector_type(8))) short;
using f32x4  = __attribute__((ext_vector_type(4))) float;

__device__ inline unsigned short f2bf(float f) {
  union { float f; unsigned u; } v; v.f = f;
  unsigned r = v.u + 0x7fffu + ((v.u >> 16) & 1u);
  return (unsigned short)(r >> 16);
}

__device__ inline f32x4 bf4_to_f32(uint2 p) {
  union { unsigned u; float f; } c;
  f32x4 r;
  c.u = (p.x & 0xffffu) << 16;  r[0] = c.f;
  c.u = (p.x & 0xffff0000u);    r[1] = c.f;
  c.u = (p.y & 0xffffu) << 16;  r[2] = c.f;
  c.u = (p.y & 0xffff0000u);    r[3] = c.f;
  return r;
}

// Wt slots: self [9][64][64] @0, aff @36864, rel [9][64][128] @73728,
//           agg [9][64][128] @147456.
__global__ __launch_bounds__(256) void prep_w(
    const float* __restrict__ Wr, const float* __restrict__ Ws,
    const float* __restrict__ Wa, const float* __restrict__ Wg,
    unsigned short* __restrict__ Wt)
{
  int i4 = (blockIdx.x * 256 + threadIdx.x) * 4;
  if (i4 >= 221184) return;
  unsigned short o4[4];
#pragma unroll
  for (int e = 0; e < 4; ++e) {
    int idx = i4 + e;
    float v;
    if (idx < 73728) {
      int c = idx / 36864, r = idx % 36864;
      int t = r >> 12, oc = (r >> 6) & 63, ic = r & 63;
      v = (c == 0 ? Ws : Wa)[oc * 576 + ic * 9 + t];
    } else {
      int r2 = idx - 73728;
      int half = r2 / 73728, rr = r2 % 73728;
      int t = rr >> 13, oc = (rr >> 7) & 63, ic = rr & 127;
      v = (half ? Wg : Wr)[oc * 1152 + ic * 9 + t];
    }
    o4[e] = f2bf(v);
  }
  uint2 pk;
  pk.x = (unsigned)o4[0] | ((unsigned)o4[1] << 16);
  pk.y = (unsigned)o4[2] | ((unsigned)o4[3] << 16);
  *(uint2*)(Wt + i4) = pk;
}

// batch b pinned to XCD b&7 (perf heuristic; correctness never depends on it)
__device__ inline void decode_img(int j, int& b, int& o) {
  b = ((j >> 7) << 3) | (j & 7);
  o = (j >> 3) & 15;
}

// stage x (fp32 [ic][px]) -> LDS bf16 [px][stride ROWX], cols at +coff.
// 512-thread version: each thread writes 4 u32 (8 ic-values) for its px.
template<int ROWX>
__device__ inline void stage_x512(const float* __restrict__ xb,
                                  unsigned short* __restrict__ s,
                                  int coff, int w8, int px) {
#pragma unroll
  for (int r = 0; r < 4; ++r) {
    int ic0 = (w8 + 8 * r) * 2;
    const float* sp = xb + ic0 * 64;
    float a = sp[px], c = sp[64 + px];
    *(unsigned*)(s + px * ROWX + coff + ic0) =
        (unsigned)f2bf(a) | ((unsigned)f2bf(c) << 16);
  }
}

__global__ __launch_bounds__(512, 4) void k1(
    const float* __restrict__ x,
    const unsigned short* __restrict__ Wt,
    unsigned short* __restrict__ cA, unsigned short* __restrict__ cB)
{
  constexpr int ROW = 72;
  __shared__ __align__(16) unsigned short sX[65 * ROW];
  int b, o;
  decode_img(blockIdx.x, b, o);
  const int img = b * 16 + o;
  const int tid = threadIdx.x;
  const int w8 = tid >> 6, lane = tid & 63;

  stage_x512<ROW>(x + (size_t)img * IMGSZ, sX, 0, w8, lane);
  if (tid < 36) ((unsigned*)(sX + 64 * ROW))[tid] = 0;
  __syncthreads();

  const int half = tid >> 8;       // waves 0-3: convA (ic 0..63); 4-7: convB
  const int w = w8 & 3;            // oc quarter
  const int q = lane >> 4, n16 = lane & 15;
  const int ocb = w * 16;
  const int co = ocb + q * 4;

  int pyt[4], pxt[4];
#pragma unroll
  for (int t = 0; t < 4; ++t) { int p = t * 16 + n16; pyt[t] = p >> 3; pxt[t] = p & 7; }

  f32x4 acc[4] = {};
  const unsigned short* WH = Wt + 73728 + (ocb + n16) * 128 + q * 8 + half * 64;
#pragma unroll
  for (int tap = 0; tap < 9; ++tap) {
    const int dy = tap / 3 - 1, dx = tap % 3 - 1;
    int spt[4];
#pragma unroll
    for (int t = 0; t < 4; ++t) {
      int sy = pyt[t] + dy, sx = pxt[t] + dx;
      spt[t] = ((unsigned)sy < 8u && (unsigned)sx < 8u) ? (sy * 8 + sx) : 64;
    }
#pragma unroll
    for (int ks = 0; ks < 2; ++ks) {
      bf16x8 aa = *(const bf16x8*)(WH + tap * 8192 + ks * 32);
#pragma unroll
      for (int t = 0; t < 4; ++t) {
        bf16x8 bt = *(const bf16x8*)(sX + spt[t] * ROW + ks * 32 + q * 8);
        acc[t] = __builtin_amdgcn_mfma_f32_16x16x32_bf16(aa, bt, acc[t], 0, 0, 0);
      }
    }
  }

  unsigned short* dst = half ? cB : cA;
  const size_t ib = (size_t)img * IMGSZ;
#pragma unroll
  for (int t = 0; t < 4; ++t) {
    int p = t * 16 + n16;
    uint2 pa;
    pa.x = (unsigned)f2bf(acc[t][0]) | ((unsigned)f2bf(acc[t][1]) << 16);
    pa.y = (unsigned)f2bf(acc[t][2]) | ((unsigned)f2bf(acc[t][3]) << 16);
    *(uint2*)(dst + ib + p * 64 + co) = pa;
  }
}

__global__ __launch_bounds__(512, 4) void k2(
    const float* __restrict__ x,
    const int* __restrict__ g_idx,
    const unsigned short* __restrict__ Wt,
    const float* __restrict__ b_rel, const float* __restrict__ b_self,
    const float* __restrict__ b_aff, const float* __restrict__ b_agg,
    const unsigned short* __restrict__ cA, const unsigned short* __restrict__ cB,
    float* __restrict__ out)
{
  constexpr int ROW = 72, ROW2 = 136, XROW = 68;
  __shared__ __align__(16) unsigned short sX[65 * ROW2];   // [a | x] bf16
  __shared__ __align__(16) unsigned short sPred[65 * ROW]; // pred bf16
  __shared__ __align__(16) float sXS[64 * XROW];           // xs fp32
  __shared__ int so1a[16], so2a[16];                        // compacted m=1 pairs
  __shared__ float sma[16];                                 // 1 active / 0 pad
  __shared__ int s_na;

  int b, i;
  decode_img(blockIdx.x, b, i);
  const int img = b * 16 + i;
  const int tid = threadIdx.x;
  const int w8 = tid >> 6, lane = tid & 63;

  // ---- mask compaction (wave 0): g_idx col2 is exactly 0/1, block-uniform.
  // m=0 pairs fold into the constant (15-na)*relu(br); only m=1 pairs load.
  int o1v = 0, o2v = 0, mv = 0;
  if (tid < 15) {
    const int* gp = g_idx + ((size_t)b * 240 + i * 15 + tid) * 3;
    o1v = gp[0] & 15;   // tile(x, n-1): x1[j] = x[j % 16]
    o2v = gp[1] & 15;
    mv  = gp[2];
  }
  if (tid < 64) {
    if (tid < 16) { so1a[tid] = 0; so2a[tid] = 0; sma[tid] = 0.f; }
    unsigned long long mk = __ballot(mv != 0);
    int pfx = (int)__popcll(mk & ((1ull << tid) - 1));
    if (mv) { so1a[pfx] = o1v; so2a[pfx] = o2v; sma[pfx] = 1.f; }
    if (tid == 0) s_na = (int)__popcll(mk);
  }

  stage_x512<ROW2>(x + (size_t)img * IMGSZ, sX, 64, w8, lane);
  if (tid < 68) ((unsigned*)(sX + 64 * ROW2))[tid] = 0;
  if (tid < 36) ((unsigned*)(sPred + 64 * ROW))[tid] = 0;
  __syncthreads();

  const int w = w8 & 3;
  const int q = lane >> 4, n16 = lane & 15;
  const int ocb = w * 16;
  const int co = ocb + q * 4;
  const int aw64  = (ocb + n16) * 64 + q * 8;
  const int aw128 = (ocb + n16) * 128 + q * 8;

  int pyt[4], pxt[4];
#pragma unroll
  for (int t = 0; t < 4; ++t) { int p = t * 16 + n16; pyt[t] = p >> 3; pxt[t] = p & 7; }

  // ---- self conv (waves 0-3) -> xs in LDS fp32
  if (tid < 256) {
    f32x4 f[4] = {};
    const unsigned short* WS = Wt + aw64;
#pragma unroll
    for (int tap = 0; tap < 9; ++tap) {
      const int dy = tap / 3 - 1, dx = tap % 3 - 1;
      int spt[4];
#pragma unroll
      for (int t = 0; t < 4; ++t) {
        int sy = pyt[t] + dy, sx = pxt[t] + dx;
        spt[t] = ((unsigned)sy < 8u && (unsigned)sx < 8u) ? (sy * 8 + sx) : 64;
      }
#pragma unroll
      for (int ks = 0; ks < 2; ++ks) {
        bf16x8 a = *(const bf16x8*)(WS + tap * 4096 + ks * 32);
#pragma unroll
        for (int t = 0; t < 4; ++t) {
          bf16x8 bt = *(const bf16x8*)(sX + spt[t] * ROW2 + 64 + ks * 32 + q * 8);
          f[t] = __builtin_amdgcn_mfma_f32_16x16x32_bf16(a, bt, f[t], 0, 0, 0);
        }
      }
    }
#pragma unroll
    for (int t = 0; t < 4; ++t) {
      int p = t * 16 + n16;
      f32x4 vs = f[t];
#pragma unroll
      for (int r = 0; r < 4; ++r) vs[r] = fmaxf(vs[r] + b_self[co + r], 0.f);
      *(f32x4*)(sXS + p * XROW + co) = vs;
    }
  }
  __syncthreads();

  // ---- combine (all 8 waves, 2 passes): pred = xs + (15-na)*relu(br)
  //                     + sum_{active j} relu(cA[o1_j]+cB[o2_j]+br)
  {
    const size_t bb = (size_t)b * 16 * IMGSZ;
    const int na = s_na;
    const int nc = (na + 3) >> 2;
    const float c0 = (float)(15 - na);
#pragma unroll 1
    for (int pass = 0; pass < 2; ++pass) {
      const int e = tid * 4 + pass * 2048;   // 4 consecutive [px][ic] elems
      const int e_px = e >> 6, e_ic = e & 63;
      f32x4 xv = *(const f32x4*)(sXS + e_px * XROW + e_ic);
      float acc[4], br[4];
#pragma unroll
      for (int r = 0; r < 4; ++r) {
        br[r] = b_rel[e_ic + r];
        acc[r] = xv[r] + c0 * fmaxf(br[r], 0.f);
      }
#pragma unroll 1
      for (int c = 0; c < nc; ++c) {
        uint2 v1[4], v2[4];
#pragma unroll
        for (int jj = 0; jj < 4; ++jj) {
          int j = c * 4 + jj;
          v1[jj] = *(const uint2*)(cA + bb + (size_t)so1a[j] * IMGSZ + e);
          v2[jj] = *(const uint2*)(cB + bb + (size_t)so2a[j] * IMGSZ + e);
        }
#pragma unroll
        for (int jj = 0; jj < 4; ++jj) {
          float s = sma[c * 4 + jj];   // active pairs have m==1; pads 0
          f32x4 a1 = bf4_to_f32(v1[jj]);
          f32x4 a2 = bf4_to_f32(v2[jj]);
#pragma unroll
          for (int r = 0; r < 4; ++r)
            acc[r] += s * fmaxf(a1[r] + a2[r] + br[r], 0.f);
        }
      }
      uint2 pk;
      pk.x = (unsigned)f2bf(acc[0]) | ((unsigned)f2bf(acc[1]) << 16);
      pk.y = (unsigned)f2bf(acc[2]) | ((unsigned)f2bf(acc[3]) << 16);
      *(uint2*)(sPred + e_px * ROW + e_ic) = pk;
    }
  }
  __syncthreads();

  // ---- aff conv (waves 0-3): sPred -> a -> sX cols 0..63
  if (tid < 256) {
    f32x4 f[4] = {};
    const unsigned short* WA = Wt + 36864 + aw64;
#pragma unroll
    for (int tap = 0; tap < 9; ++tap) {
      const int dy = tap / 3 - 1, dx = tap % 3 - 1;
      int spt[4];
#pragma unroll
      for (int t = 0; t < 4; ++t) {
        int sy = pyt[t] + dy, sx = pxt[t] + dx;
        spt[t] = ((unsigned)sy < 8u && (unsigned)sx < 8u) ? (sy * 8 + sx) : 64;
      }
#pragma unroll
      for (int ks = 0; ks < 2; ++ks) {
        bf16x8 a = *(const bf16x8*)(WA + tap * 4096 + ks * 32);
#pragma unroll
        for (int t = 0; t < 4; ++t) {
          bf16x8 bt = *(const bf16x8*)(sPred + spt[t] * ROW + ks * 32 + q * 8);
          f[t] = __builtin_amdgcn_mfma_f32_16x16x32_bf16(a, bt, f[t], 0, 0, 0);
        }
      }
    }
#pragma unroll
    for (int t = 0; t < 4; ++t) {
      int p = t * 16 + n16;
      float v0 = fmaxf(f[t][0] + b_aff[co + 0], 0.f);
      float v1 = fmaxf(f[t][1] + b_aff[co + 1], 0.f);
      float v2 = fmaxf(f[t][2] + b_aff[co + 2], 0.f);
      float v3 = fmaxf(f[t][3] + b_aff[co + 3], 0.f);
      uint2 pk;
      pk.x = (unsigned)f2bf(v0) | ((unsigned)f2bf(v1) << 16);
      pk.y = (unsigned)f2bf(v2) | ((unsigned)f2bf(v3) << 16);
      *(uint2*)(sX + p * ROW2 + co) = pk;
    }
  }
  __syncthreads();

  // ---- agg conv (waves 0-3): sX (128 ic: [a|x]) -> out. Swapped MFMA
  // operands: lane owns 4 consecutive px of one oc -> coalesced float4.
  if (tid < 256) {
    f32x4 g[4] = {};
    const unsigned short* WG = Wt + 147456 + aw128;
#pragma unroll
    for (int tap = 0; tap < 9; ++tap) {
      const int dy = tap / 3 - 1, dx = tap % 3 - 1;
      int spt[4];
#pragma unroll
      for (int t = 0; t < 4; ++t) {
        int sy = pyt[t] + dy, sx = pxt[t] + dx;
        spt[t] = ((unsigned)sy < 8u && (unsigned)sx < 8u) ? (sy * 8 + sx) : 64;
      }
#pragma unroll
      for (int ks = 0; ks < 4; ++ks) {
        bf16x8 a = *(const bf16x8*)(WG + tap * 8192 + ks * 32);
#pragma unroll
        for (int t = 0; t < 4; ++t) {
          bf16x8 bt = *(const bf16x8*)(sX + spt[t] * ROW2 + ks * 32 + q * 8);
          g[t] = __builtin_amdgcn_mfma_f32_16x16x32_bf16(bt, a, g[t], 0, 0, 0);
        }
      }
    }
    float* ob = out + (size_t)img * IMGSZ;
    const float bg = b_agg[ocb + n16];
#pragma unroll
    for (int t = 0; t < 4; ++t) {
      f32x4 v;
#pragma unroll
      for (int r = 0; r < 4; ++r) v[r] = fmaxf(g[t][r] + bg, 0.f);
      *(f32x4*)(ob + (ocb + n16) * 64 + t * 16 + q * 4) = v;
    }
  }
}

extern "C" void kernel_launch(void* const* d_in, const int* in_sizes, int n_in,
                              void* d_out, int out_size, void* d_ws, size_t ws_size,
                              hipStream_t stream) {
  const float* x      = (const float*)d_in[0];
  const int*   g_idx  = (const int*)  d_in[1];
  const float* W_rel  = (const float*)d_in[2];
  const float* b_rel  = (const float*)d_in[3];
  const float* W_self = (const float*)d_in[4];
  const float* b_self = (const float*)d_in[5];
  const float* W_aff  = (const float*)d_in[6];
  const float* b_aff  = (const float*)d_in[7];
  const float* W_agg  = (const float*)d_in[8];
  const float* b_agg  = (const float*)d_in[9];
  float* out = (float*)d_out;

  unsigned short* cA = (unsigned short*)d_ws;      // [512][64][64] bf16
  unsigned short* cB = cA + 2097152;
  unsigned short* Wt = cB + 2097152;               // 221184 bf16

  prep_w<<<216, 256, 0, stream>>>(W_rel, W_self, W_aff, W_agg, Wt);
  k1<<<NIMG, 512, 0, stream>>>(x, Wt, cA, cB);
  k2<<<NIMG, 512, 0, stream>>>(x, g_idx, Wt, b_rel, b_self, b_aff, b_agg,
                               cA, cB, out);
}